// Round 16
// baseline (106.533 us; speedup 1.0000x reference)
//
#include <hip/hip_runtime.h>

#define RES 128
#define MAP_NUM 128
#define MAP_OFFSET (RES * RES)
#define NROWS (MAP_NUM * MAP_OFFSET)          // 2,097,152 cells
#define QUAD8_BYTES ((size_t)NROWS * 32)      // fp8 quad table: 67 MB
#define QUAD4_BYTES ((size_t)NROWS * 16)      // fp4 quad table: 33.5 MB
#define SCALE8 256.0f
#define INV_SCALE8 (1.0f / 256.0f)
#define SCALE4 2048.0f
#define INV_SCALE4 (1.0f / 2048.0f)

typedef float v2f __attribute__((ext_vector_type(2)));
typedef float v4f __attribute__((ext_vector_type(4)));
typedef unsigned int v4u __attribute__((ext_vector_type(4)));

typedef const __attribute__((address_space(1))) void* as1cv;
typedef __attribute__((address_space(3))) void* as3v;

#if defined(__has_builtin)
#if __has_builtin(__builtin_amdgcn_cvt_scalef32_pk_f32_fp4) && \
    __has_builtin(__builtin_amdgcn_cvt_scalef32_pk_fp4_f32)
#define HAS_FP4 1
#endif
#endif

#ifdef HAS_FP4
// ---------------- fp4 pack: f32 -> e2m1 quad-cell table (16B/cell) ----------
// cell (m,i,j) -> 4 words; word c = corner c (8 feats, 2 nibbles/byte).
// XCD-aligned (block g%8 packs XCD g%8's 16 maps) with NORMAL stores ->
// whole 4MB/XCD table (both map-groups) left L2-resident for the gather.
__global__ __launch_bounds__(256) void pack_quad_fp4(
    const float* __restrict__ emb,
    unsigned int* __restrict__ quad)
{
    int g = blockIdx.x;
    int x = g & 7;                   // XCD id (dispatch round-robin)
    int t = g >> 3;                  // 0..1023 per XCD
    int group = (x << 1) + (t >> 9); // map-group (8 maps)
    int c  = t & 511;
    int cell = (group << 17) + (c << 8) + threadIdx.x;

    const int MAXROW = NROWS - 1;
    unsigned int w[4];
    #pragma unroll
    for (int cnr = 0; cnr < 4; ++cnr) {
        int r = cell + (cnr & 1) * RES + (cnr >> 1);
        r = min(r, MAXROW);          // edge cells unused; stay in-bounds
        const v4f* p = reinterpret_cast<const v4f*>(emb) + 2 * (size_t)r;
        v4f a = p[0] * SCALE4;
        v4f b = p[1] * SCALE4;
        unsigned int wd = 0;
        wd = __builtin_amdgcn_cvt_scalef32_pk_fp4_f32(wd, a.x, a.y, 1.0f, 0);
        wd = __builtin_amdgcn_cvt_scalef32_pk_fp4_f32(wd, a.z, a.w, 1.0f, 1);
        wd = __builtin_amdgcn_cvt_scalef32_pk_fp4_f32(wd, b.x, b.y, 1.0f, 2);
        wd = __builtin_amdgcn_cvt_scalef32_pk_fp4_f32(wd, b.z, b.w, 1.0f, 3);
        w[cnr] = wd;
    }
    v4u* dst = reinterpret_cast<v4u*>(quad) + (size_t)cell;
    dst[0] = v4u{w[0], w[1], w[2], w[3]};    // normal store: stays in own L2
}

// ---------------- fp4 gather: ONE 16B load per item --------------------------
// r15 structure: block = 256 threads x 2 items = 64 batch x 8 maps; thread
// handles (b,m),(b,m+1); one 16B input load feeds both. Whole cell = one v4u
// (word c = corner c). Subtable 2MB/group -> both groups of an XCD L2-resident
// from pack; no prefetch, no ordering needed. LDS-staged full-line nt output.
__global__ __launch_bounds__(256) void densemap_fwd_q4(
    const float* __restrict__ inputs,
    const unsigned int* __restrict__ quad,
    float* __restrict__ out)
{
    __shared__ float lds[64 * 80];   // 20480 B output staging

    int g = blockIdx.x;
    int x  = g & 7;          // XCD id (dispatch round-robin)
    int t  = g >> 3;         // 0..1023 per XCD
    int gl = t >> 9;
    int c  = t & 511;        // b-chunk within group
    int m0 = ((x << 1) + gl) << 3;   // first map of 8-map group
    int b0 = c << 6;                 // 64 batch items per block

    int mi2 = (threadIdx.x & 3) << 1;      // 0,2,4,6 : map pair within group
    int bi  = threadIdx.x >> 2;            // 0..63   : batch within block

    const v4f* inp4 = reinterpret_cast<const v4f*>(
        inputs + ((size_t)(b0 + bi) * MAP_NUM + (m0 + mi2)) * 2);
    v4f in4 = __builtin_nontemporal_load(inp4);

    const v4u* q4 = reinterpret_cast<const v4u*>(quad);
    __attribute__((aligned(16))) float fo[20];   // staged 2-item record (80B)

    #pragma unroll
    for (int s = 0; s < 2; ++s) {
        float xin0 = (s == 0) ? in4.x : in4.z;
        float xin1 = (s == 0) ? in4.y : in4.w;
        float x0 = xin0 * (float)(RES - 1);
        float x1 = xin1 * (float)(RES - 1);
        int xi0 = (int)x0;
        int xi1 = (int)x1;
        float xf0 = x0 - (float)xi0;
        float xf1 = x1 - (float)xi1;

        int cell = ((m0 + mi2 + s) << 14) + (xi0 << 7) + xi1;
        v4u d = q4[cell];
        // d.x=c0(i,j)  d.y=c1(i+1,j)  d.z=c2(i,j+1)  d.w=c3(i+1,j+1)

        float w00 = (1.0f - xf0) * (1.0f - xf1) * INV_SCALE4;
        float w10 = xf0 * (1.0f - xf1) * INV_SCALE4;
        float w01 = (1.0f - xf0) * xf1 * INV_SCALE4;
        float w11 = xf0 * xf1 * INV_SCALE4;

        v2f f01 = __builtin_amdgcn_cvt_scalef32_pk_f32_fp4(d.x, 1.0f, 0) * w00
                + __builtin_amdgcn_cvt_scalef32_pk_f32_fp4(d.y, 1.0f, 0) * w10
                + __builtin_amdgcn_cvt_scalef32_pk_f32_fp4(d.z, 1.0f, 0) * w01
                + __builtin_amdgcn_cvt_scalef32_pk_f32_fp4(d.w, 1.0f, 0) * w11;
        v2f f23 = __builtin_amdgcn_cvt_scalef32_pk_f32_fp4(d.x, 1.0f, 1) * w00
                + __builtin_amdgcn_cvt_scalef32_pk_f32_fp4(d.y, 1.0f, 1) * w10
                + __builtin_amdgcn_cvt_scalef32_pk_f32_fp4(d.z, 1.0f, 1) * w01
                + __builtin_amdgcn_cvt_scalef32_pk_f32_fp4(d.w, 1.0f, 1) * w11;
        v2f f45 = __builtin_amdgcn_cvt_scalef32_pk_f32_fp4(d.x, 1.0f, 2) * w00
                + __builtin_amdgcn_cvt_scalef32_pk_f32_fp4(d.y, 1.0f, 2) * w10
                + __builtin_amdgcn_cvt_scalef32_pk_f32_fp4(d.z, 1.0f, 2) * w01
                + __builtin_amdgcn_cvt_scalef32_pk_f32_fp4(d.w, 1.0f, 2) * w11;
        v2f f67 = __builtin_amdgcn_cvt_scalef32_pk_f32_fp4(d.x, 1.0f, 3) * w00
                + __builtin_amdgcn_cvt_scalef32_pk_f32_fp4(d.y, 1.0f, 3) * w10
                + __builtin_amdgcn_cvt_scalef32_pk_f32_fp4(d.z, 1.0f, 3) * w01
                + __builtin_amdgcn_cvt_scalef32_pk_f32_fp4(d.w, 1.0f, 3) * w11;

        fo[s * 10 + 0] = f01.x;  fo[s * 10 + 1] = f01.y;
        fo[s * 10 + 2] = f23.x;  fo[s * 10 + 3] = f23.y;
        fo[s * 10 + 4] = f45.x;  fo[s * 10 + 5] = f45.y;
        fo[s * 10 + 6] = f67.x;  fo[s * 10 + 7] = f67.y;
        fo[s * 10 + 8] = xf0;    fo[s * 10 + 9] = xf1;
    }

    {   // stage 80B contiguous (two adjacent-map records), 16B-aligned
        v4f* dst = reinterpret_cast<v4f*>(lds + bi * 80 + mi2 * 10);
        const v4f* src = reinterpret_cast<const v4f*>(fo);
        #pragma unroll
        for (int k = 0; k < 5; ++k) dst[k] = src[k];
    }

    __syncthreads();

    // write out 1280 float4 (= 64 segments x 20), full-line nt stores
    const v4f* l4 = reinterpret_cast<const v4f*>(lds);
    float* ob = out + ((size_t)b0 * MAP_NUM + m0) * 10;  // 320B-aligned
    #pragma unroll
    for (int it = 0; it < 5; ++it) {
        int j = threadIdx.x + it * 256;
        int seg = j / 20;
        int wi  = j - seg * 20;
        v4f val = l4[j];
        float* dst = ob + (size_t)seg * (MAP_NUM * 10) + wi * 4;
        __builtin_nontemporal_store(val, reinterpret_cast<v4f*>(dst));
    }
}
#endif  // HAS_FP4

// ---------------- fp8 pack + gather (r15 versions, fallback path) ------------
__global__ __launch_bounds__(256) void pack_quad_fp8(
    const float* __restrict__ emb,
    unsigned int* __restrict__ quad)
{
    int g = blockIdx.x;
    int x = g & 7;
    int t = g >> 3;
    int gl = (t < 512) ? 1 : 0;
    int c  = (t & 511);
    int group = (x << 1) + gl;
    int cell = (group << 17) + c * 256 + threadIdx.x;

    const int MAXROW = NROWS - 1;
    unsigned int w[8];
    #pragma unroll
    for (int cnr = 0; cnr < 4; ++cnr) {
        int r = cell + (cnr & 1) * RES + (cnr >> 1);
        r = min(r, MAXROW);
        const v4f* p = reinterpret_cast<const v4f*>(emb) + 2 * (size_t)r;
        v4f a = p[0] * SCALE8;
        v4f b = p[1] * SCALE8;
        int w0 = __builtin_amdgcn_cvt_pk_fp8_f32(a.x, a.y, 0, false);
        w0     = __builtin_amdgcn_cvt_pk_fp8_f32(a.z, a.w, w0, true);
        int w1 = __builtin_amdgcn_cvt_pk_fp8_f32(b.x, b.y, 0, false);
        w1     = __builtin_amdgcn_cvt_pk_fp8_f32(b.z, b.w, w1, true);
        w[cnr * 2]     = (unsigned int)w0;
        w[cnr * 2 + 1] = (unsigned int)w1;
    }
    v4u* dst = reinterpret_cast<v4u*>(quad) + 2 * (size_t)cell;
    dst[0] = v4u{w[0], w[1], w[2], w[3]};
    dst[1] = v4u{w[4], w[5], w[6], w[7]};
}

__global__ __launch_bounds__(256) void densemap_fwd_q8(
    const float* __restrict__ inputs,
    const unsigned int* __restrict__ quad,
    float* __restrict__ out)
{
    __shared__ float lds[64 * 80];
    __shared__ v4u pfbuf[64];

    int g = blockIdx.x;
    int x  = g & 7;
    int t  = g >> 3;
    int gl = t >> 9;
    int c  = t & 511;
    int m0 = ((x << 1) + gl) << 3;
    int b0 = c << 6;

    if (gl == 1 && threadIdx.x < 64) {
        const char* sbase = reinterpret_cast<const char*>(quad)
                          + ((size_t)(((x << 1) + gl) << 17)) * 32
                          + (size_t)c * 8192;
        #pragma unroll
        for (int p = 0; p < 8; ++p) {
            __builtin_amdgcn_global_load_lds(
                (as1cv)(sbase + p * 1024 + (threadIdx.x & 63) * 16),
                (as3v)pfbuf, 16, 0, 0);
        }
    }

    int mi2 = (threadIdx.x & 3) << 1;
    int bi  = threadIdx.x >> 2;

    const v4f* inp4 = reinterpret_cast<const v4f*>(
        inputs + ((size_t)(b0 + bi) * MAP_NUM + (m0 + mi2)) * 2);
    v4f in4 = __builtin_nontemporal_load(inp4);

    const v4u* q4 = reinterpret_cast<const v4u*>(quad);
    __attribute__((aligned(16))) float fo[20];

    #pragma unroll
    for (int s = 0; s < 2; ++s) {
        float xin0 = (s == 0) ? in4.x : in4.z;
        float xin1 = (s == 0) ? in4.y : in4.w;
        float x0 = xin0 * (float)(RES - 1);
        float x1 = xin1 * (float)(RES - 1);
        int xi0 = (int)x0;
        int xi1 = (int)x1;
        float xf0 = x0 - (float)xi0;
        float xf1 = x1 - (float)xi1;

        int cell = ((m0 + mi2 + s) << 14) + (xi0 << 7) + xi1;
        v4u d0 = q4[2 * cell];
        v4u d1 = q4[2 * cell + 1];

        float w00 = (1.0f - xf0) * (1.0f - xf1) * INV_SCALE8;
        float w10 = xf0 * (1.0f - xf1) * INV_SCALE8;
        float w01 = (1.0f - xf0) * xf1 * INV_SCALE8;
        float w11 = xf0 * xf1 * INV_SCALE8;

        v2f f01 = __builtin_amdgcn_cvt_pk_f32_fp8((int)d0.x, false) * w00
                + __builtin_amdgcn_cvt_pk_f32_fp8((int)d0.z, false) * w10
                + __builtin_amdgcn_cvt_pk_f32_fp8((int)d1.x, false) * w01
                + __builtin_amdgcn_cvt_pk_f32_fp8((int)d1.z, false) * w11;
        v2f f23 = __builtin_amdgcn_cvt_pk_f32_fp8((int)d0.x, true)  * w00
                + __builtin_amdgcn_cvt_pk_f32_fp8((int)d0.z, true)  * w10
                + __builtin_amdgcn_cvt_pk_f32_fp8((int)d1.x, true)  * w01
                + __builtin_amdgcn_cvt_pk_f32_fp8((int)d1.z, true)  * w11;
        v2f f45 = __builtin_amdgcn_cvt_pk_f32_fp8((int)d0.y, false) * w00
                + __builtin_amdgcn_cvt_pk_f32_fp8((int)d0.w, false) * w10
                + __builtin_amdgcn_cvt_pk_f32_fp8((int)d1.y, false) * w01
                + __builtin_amdgcn_cvt_pk_f32_fp8((int)d1.w, false) * w11;
        v2f f67 = __builtin_amdgcn_cvt_pk_f32_fp8((int)d0.y, true)  * w00
                + __builtin_amdgcn_cvt_pk_f32_fp8((int)d0.w, true)  * w10
                + __builtin_amdgcn_cvt_pk_f32_fp8((int)d1.y, true)  * w01
                + __builtin_amdgcn_cvt_pk_f32_fp8((int)d1.w, true)  * w11;

        fo[s * 10 + 0] = f01.x;  fo[s * 10 + 1] = f01.y;
        fo[s * 10 + 2] = f23.x;  fo[s * 10 + 3] = f23.y;
        fo[s * 10 + 4] = f45.x;  fo[s * 10 + 5] = f45.y;
        fo[s * 10 + 6] = f67.x;  fo[s * 10 + 7] = f67.y;
        fo[s * 10 + 8] = xf0;    fo[s * 10 + 9] = xf1;
    }

    {
        v4f* dst = reinterpret_cast<v4f*>(lds + bi * 80 + mi2 * 10);
        const v4f* src = reinterpret_cast<const v4f*>(fo);
        #pragma unroll
        for (int k = 0; k < 5; ++k) dst[k] = src[k];
    }

    __syncthreads();

    const v4f* l4 = reinterpret_cast<const v4f*>(lds);
    float* ob = out + ((size_t)b0 * MAP_NUM + m0) * 10;
    #pragma unroll
    for (int it = 0; it < 5; ++it) {
        int j = threadIdx.x + it * 256;
        int seg = j / 20;
        int wi  = j - seg * 20;
        v4f val = l4[j];
        float* dst = ob + (size_t)seg * (MAP_NUM * 10) + wi * 4;
        __builtin_nontemporal_store(val, reinterpret_cast<v4f*>(dst));
    }
}

// ---------------- fallback (r8 kernel) if ws is too small ----------------
__global__ __launch_bounds__(256, 4) void densemap_fwd_fb(
    const float* __restrict__ inputs,
    const float* __restrict__ emb,
    float* __restrict__ out)
{
    __shared__ float lds[32 * 80];

    int g = blockIdx.x;
    int x  = g & 7;
    int t  = g >> 3;
    int gl = t >> 10;
    int c  = t & 1023;
    int m0 = ((x << 1) + gl) << 3;
    int b0 = c << 5;

    int lane   = threadIdx.x & 7;
    int grp    = threadIdx.x >> 3;
    int corner = lane >> 1;
    int h      = lane & 1;

    int mi = grp & 7;
    int m  = m0 + mi;
    int biBase = b0 + (grp >> 3);

    const v2f* inp2 = reinterpret_cast<const v2f*>(inputs);
    const v4f* e4   = reinterpret_cast<const v4f*>(emb);

    v2f in2[8];
    #pragma unroll
    for (int r = 0; r < 8; ++r) {
        int idx = (biBase + 4 * r) * MAP_NUM + m;
        in2[r] = __builtin_nontemporal_load(inp2 + idx);
    }
    __builtin_amdgcn_sched_barrier(0);

    float xf0a[8], xf1a[8];
    v4f row[8];
    int mbase = m * MAP_OFFSET;
    #pragma unroll
    for (int r = 0; r < 8; ++r) {
        float x0 = in2[r].x * (float)(RES - 1);
        float x1 = in2[r].y * (float)(RES - 1);
        int xi0 = (int)x0;
        int xi1 = (int)x1;
        xf0a[r] = x0 - (float)xi0;
        xf1a[r] = x1 - (float)xi1;
        int base = mbase + xi0 * RES + xi1;
        int pidx = 2 * (base + (corner & 1) * RES + (corner >> 1)) + h;
        row[r] = e4[pidx];
    }
    __builtin_amdgcn_sched_barrier(0);

    #pragma unroll
    for (int r = 0; r < 8; ++r) {
        float xf0 = xf0a[r];
        float xf1 = xf1a[r];
        float w0 = (corner & 1) ? xf0 : 1.0f - xf0;
        float w1 = (corner & 2) ? xf1 : 1.0f - xf1;
        v4f S = row[r] * (w0 * w1);
        #pragma unroll
        for (int k = 0; k < 4; ++k) S[k] += __shfl_xor(S[k], 2);
        #pragma unroll
        for (int k = 0; k < 4; ++k) S[k] += __shfl_xor(S[k], 4);
        int bi = (grp >> 3) + 4 * r;
        if (lane < 5) {
            int p = (lane == 4) ? 4 : (((lane & 1) << 1) | (lane >> 1));
            v2f val;
            if (lane == 4)     val = v2f{xf0, xf1};
            else if (lane & 2) val = v2f{S.z, S.w};
            else               val = v2f{S.x, S.y};
            *reinterpret_cast<v2f*>(lds + bi * 80 + mi * 10 + p * 2) = val;
        }
    }

    __syncthreads();

    const v4f* l4 = reinterpret_cast<const v4f*>(lds);
    float* ob = out + ((size_t)b0 * MAP_NUM + m0) * 10;
    for (int j = threadIdx.x; j < 640; j += 256) {
        int seg = j / 20;
        int wi  = j - seg * 20;
        v4f val = l4[j];
        float* dst = ob + (size_t)seg * (MAP_NUM * 10) + wi * 4;
        __builtin_nontemporal_store(val, reinterpret_cast<v4f*>(dst));
    }
}

extern "C" void kernel_launch(void* const* d_in, const int* in_sizes, int n_in,
                              void* d_out, int out_size, void* d_ws, size_t ws_size,
                              hipStream_t stream) {
    const float* inputs = (const float*)d_in[0];      // 32768*128*2
    const float* emb    = (const float*)d_in[1];      // 128*16384*8
    float* out          = (float*)d_out;              // 32768*128*10

#ifdef HAS_FP4
    if (ws_size >= QUAD4_BYTES) {
        unsigned int* quad = (unsigned int*)d_ws;
        pack_quad_fp4<<<NROWS / 256, 256, 0, stream>>>(emb, quad);
        densemap_fwd_q4<<<8192, 256, 0, stream>>>(inputs, quad, out);
        return;
    }
#else
    if (ws_size >= QUAD8_BYTES) {
        unsigned int* quad = (unsigned int*)d_ws;
        pack_quad_fp8<<<NROWS / 256, 256, 0, stream>>>(emb, quad);
        densemap_fwd_q8<<<8192, 256, 0, stream>>>(inputs, quad, out);
        return;
    }
#endif
    densemap_fwd_fb<<<16384, 256, 0, stream>>>(inputs, emb, out);
}